// Round 7
// baseline (423.283 us; speedup 1.0000x reference)
//
#include <hip/hip_runtime.h>

typedef __attribute__((ext_vector_type(4))) float f32x4;
typedef __attribute__((ext_vector_type(8))) __bf16 bf16x8;
typedef __attribute__((ext_vector_type(8))) unsigned short us8;
typedef unsigned short u16;

#define SSILU_SCALE (1.0f / 0.6f)
#define INV_SQRT2 0.70710678118654752f

__device__ __forceinline__ u16 f2bf(float f) {
    __bf16 h = (__bf16)f;
    return __builtin_bit_cast(u16, h);
}
__device__ __forceinline__ float bf2f(u16 h) {
    union { unsigned int u; float f; } v; v.u = ((unsigned int)h) << 16;
    return v.f;
}
__device__ __forceinline__ float ssilu(float x) {
    float e = __expf(-x);
    float s = __builtin_amdgcn_rcpf(1.0f + e);
    return x * s * SSILU_SCALE;
}

// ---------------------------------------------------------------------------
// prep: (unchanged layouts)
//  WinF : W_in as B-fragments [kt20][w4][kk2][n4][lane64][8]
//  Wfrag: 4 resid matrices as [g][w4][kk8][n4][lane64][8]
// ---------------------------------------------------------------------------
__global__ __launch_bounds__(256) void prep_kernel(
    const float* __restrict__ Win, const float* __restrict__ W1a,
    const float* __restrict__ W1b, const float* __restrict__ W2a,
    const float* __restrict__ W2b, u16* __restrict__ WinF,
    u16* __restrict__ Wfrag, float* __restrict__ out, int outN) {
    int i = blockIdx.x * 256 + threadIdx.x;
    if (i < 327680) {
        int e = i & 7, lane = (i >> 3) & 63, n = (i >> 9) & 3;
        int kk = (i >> 11) & 1, w = (i >> 12) & 3, kt = i >> 14;
        int lo = lane & 15, hi = lane >> 4;
        int k = kt * 64 + kk * 32 + hi * 8 + e;
        int col = w * 64 + n * 16 + lo;
        WinF[i] = f2bf(Win[k * 256 + col]);
        return;
    }
    int j = i - 327680;
    if (j < 262144) {
        int g = j >> 16, r = j & 65535;
        int chunk = r >> 9, within = r & 511;
        int lane = within >> 3, e = within & 7;
        int w = chunk >> 5, kk = (chunk >> 2) & 7, n = chunk & 3;
        int lo = lane & 15, hi = lane >> 4;
        int col = w * 64 + n * 16 + lo;
        int k = kk * 32 + hi * 8 + e;
        const float* W = (g == 0) ? W1a : (g == 1) ? W1b : (g == 2) ? W2a : W2b;
        Wfrag[j] = f2bf(W[k * 256 + col]);
        return;
    }
    int z = j - 262144;
    if (z < outN) out[z] = 0.0f;
}

// ---------------------------------------------------------------------------
// phase-2 GEMM: 64x256 tile, 8 waves, wave owns 32 cols. B streams from L2.
// Wfw pre-offset: Wfrag + g*65536 + (w>>1)*16384 + (w&1)*1024 + l*8
// ---------------------------------------------------------------------------
__device__ __forceinline__ void gemm_lds8(const char* AB, const u16* __restrict__ Wfw,
                                          int swz, int hi, int lo, f32x4 acc[4][2]) {
#pragma unroll
    for (int m = 0; m < 4; m++)
#pragma unroll
        for (int n = 0; n < 2; n++) acc[m][n] = (f32x4){0.f, 0.f, 0.f, 0.f};
    bf16x8 bv[2], bvn[2];
#pragma unroll
    for (int n = 0; n < 2; n++)
        bv[n] = __builtin_bit_cast(bf16x8, *(const us8*)(Wfw + n * 512));
#pragma unroll
    for (int kk = 0; kk < 8; ++kk) {
        int kbyte = kk * 64 + hi * 16;
        bf16x8 af[4];
#pragma unroll
        for (int m = 0; m < 4; m++) {
            int r = m * 16 + lo;
            af[m] = __builtin_bit_cast(bf16x8,
                *(const us8*)(AB + r * 512 + (kbyte ^ swz)));
        }
        if (kk < 7) {
#pragma unroll
            for (int n = 0; n < 2; n++)
                bvn[n] = __builtin_bit_cast(bf16x8,
                    *(const us8*)(Wfw + (kk + 1) * 2048 + n * 512));
        }
#pragma unroll
        for (int m = 0; m < 4; m++)
#pragma unroll
            for (int n = 0; n < 2; n++)
                acc[m][n] = __builtin_amdgcn_mfma_f32_16x16x32_bf16(
                    af[m], bv[n], acc[m][n], 0, 0, 0);
        if (kk < 7) {
#pragma unroll
            for (int n = 0; n < 2; n++) bv[n] = bvn[n];
        }
    }
}

// ---------------------------------------------------------------------------
// fused: 64 edge-rows, 8 waves (wave w -> cols 32w..32w+31).
// Phase 1: 2-deep A prefetch (reg dbuf) + 1-deep B prefetch, raw barriers,
//          no vmcnt drains. Phase 2: residual stack on resident xb tile.
// ---------------------------------------------------------------------------
__global__ __launch_bounds__(512, 4) void fused_kernel(
    const float* __restrict__ A, const u16* __restrict__ WinF,
    const u16* __restrict__ Wfrag, const float* __restrict__ Wout,
    const float* __restrict__ evec, const int* __restrict__ eidx,
    float* __restrict__ out) {
    __shared__ u16 xb[64 * 256];   // 32KB swizzled x tile (512B rows)
    __shared__ u16 tb[64 * 256];   // 32KB temp; first 16KB = A dbuf in phase 1
    __shared__ float fpart[8][64];
    const int t = threadIdx.x, w = t >> 6, l = t & 63;
    const int lo = l & 15, hi = l >> 4;
    const int swz = (lo & 7) << 4;            // A-frag row swizzle (r&7 == lo&7)
    const long rowbase = (long)blockIdx.x * 64;
    char* xbB = (char*)xb;
    char* tbB = (char*)tb;
    char* As0 = tbB;
    char* As1 = tbB + 8192;

    f32x4 acc[4][2];
#pragma unroll
    for (int m = 0; m < 4; m++)
#pragma unroll
        for (int n = 0; n < 2; n++) acc[m][n] = (f32x4){0.f, 0.f, 0.f, 0.f};

    // ---------------- phase 1: x = ssilu(x_cat @ W_in) ----------------
    const int ar = t >> 3, ak8 = (t & 7) * 8;     // this thread's A chunk
    const int awz = ((ak8 * 2) ^ ((ar & 7) << 4));
    float4 va0[2], va1[2];
    auto LOADA = [&](int kb, float4* va) {
        const float* s = A + (rowbase + ar) * 1280 + kb + ak8;
        va[0] = *(const float4*)s;
        va[1] = *(const float4*)(s + 4);
    };
    auto WRITEA = [&](char* dst, const float4* va) {
        us8 p;
        p[0] = f2bf(va[0].x); p[1] = f2bf(va[0].y);
        p[2] = f2bf(va[0].z); p[3] = f2bf(va[0].w);
        p[4] = f2bf(va[1].x); p[5] = f2bf(va[1].y);
        p[6] = f2bf(va[1].z); p[7] = f2bf(va[1].w);
        *(us8*)(dst + ar * 128 + awz) = p;
    };
    const u16* WinFw = WinF + (w >> 1) * 4096 + (w & 1) * 1024 + l * 8;
    auto LOADB = [&](int kt, bf16x8 (&b)[4]) {
        const u16* base = WinFw + kt * 16384;
#pragma unroll
        for (int kk = 0; kk < 2; ++kk)
#pragma unroll
            for (int n = 0; n < 2; ++n)
                b[kk * 2 + n] = __builtin_bit_cast(bf16x8,
                    *(const us8*)(base + kk * 2048 + n * 512));
    };
    auto MFMASTEP = [&](const char* AB, const bf16x8 (&bc)[4]) {
#pragma unroll
        for (int kk = 0; kk < 2; ++kk) {
            int kbyte = kk * 64 + hi * 16;
            bf16x8 af[4];
#pragma unroll
            for (int m = 0; m < 4; m++) {
                int r = m * 16 + lo;
                af[m] = __builtin_bit_cast(bf16x8,
                    *(const us8*)(AB + r * 128 + (kbyte ^ swz)));
            }
#pragma unroll
            for (int m = 0; m < 4; m++)
#pragma unroll
                for (int n = 0; n < 2; n++)
                    acc[m][n] = __builtin_amdgcn_mfma_f32_16x16x32_bf16(
                        af[m], bc[kk * 2 + n], acc[m][n], 0, 0, 0);
        }
    };
    auto FENCE = [&]() {
        asm volatile("s_waitcnt lgkmcnt(0)" ::: "memory");
        __builtin_amdgcn_sched_barrier(0);
        __builtin_amdgcn_s_barrier();
    };

    bf16x8 b0[4], b1[4];

    // prologue: As0 <- A(0); va0 <- A(1); va1 <- A(2); b0 <- B(0)
    LOADA(0, va1);
    WRITEA(As0, va1);
    LOADB(0, b0);
    LOADA(64, va0);
    LOADA(128, va1);
    FENCE();

    // main loop: kt = 0..15 (2 steps / iter, static reg-set parity)
    for (int i = 0; i < 8; ++i) {
        const int kt = 2 * i;
        // even step kt: read As0/b0; stage A(kt+1)=va0 -> As1; load A(kt+3)->va0
        LOADB(kt + 1, b1);
        __builtin_amdgcn_sched_barrier(0);
        MFMASTEP(As0, b0);
        WRITEA(As1, va0);
        LOADA((kt + 3) * 64, va0);
        FENCE();
        // odd step kt+1: read As1/b1; stage A(kt+2)=va1 -> As0; load A(kt+4)->va1
        LOADB(kt + 2, b0);
        __builtin_amdgcn_sched_barrier(0);
        MFMASTEP(As1, b1);
        WRITEA(As0, va1);
        LOADA((kt + 4) * 64, va1);
        FENCE();
    }
    // peeled tail: kt = 16..19 (va0=A(17), va1=A(18) at entry)
    LOADB(17, b1);
    __builtin_amdgcn_sched_barrier(0);
    MFMASTEP(As0, b0);
    WRITEA(As1, va0);
    LOADA(19 * 64, va0);
    FENCE();

    LOADB(18, b0);
    __builtin_amdgcn_sched_barrier(0);
    MFMASTEP(As1, b1);
    WRITEA(As0, va1);
    FENCE();

    LOADB(19, b1);
    __builtin_amdgcn_sched_barrier(0);
    MFMASTEP(As0, b0);
    WRITEA(As1, va0);
    FENCE();

    MFMASTEP(As1, b1);

    // epilogue: x = ssilu(acc) -> xb (swizzled); tb's A-staging role ends
#pragma unroll
    for (int m = 0; m < 4; m++)
#pragma unroll
        for (int n = 0; n < 2; n++)
#pragma unroll
            for (int j = 0; j < 4; j++) {
                int r = m * 16 + hi * 4 + j;
                int cc = w * 32 + n * 16 + lo;
                *(u16*)(xbB + r * 512 + ((cc * 2) ^ ((r & 7) << 4))) =
                    f2bf(ssilu(acc[m][n][j]));
            }
    __syncthreads();

    // ---------------- phase 2: residual stack ----------------
    const u16* Wfw = Wfrag + (w >> 1) * 16384 + (w & 1) * 1024 + l * 8;

    // G1: t1 = ssilu(x @ W1a) -> tb
    gemm_lds8(xbB, Wfw + 0 * 65536, swz, hi, lo, acc);
#pragma unroll
    for (int m = 0; m < 4; m++)
#pragma unroll
        for (int n = 0; n < 2; n++)
#pragma unroll
            for (int j = 0; j < 4; j++) {
                int r = m * 16 + hi * 4 + j;
                int cc = w * 32 + n * 16 + lo;
                *(u16*)(tbB + r * 512 + ((cc * 2) ^ ((r & 7) << 4))) =
                    f2bf(ssilu(acc[m][n][j]));
            }
    __syncthreads();

    // G2: x = (x + ssilu(t1 @ W1b)) * INV_SQRT2 -> xb
    gemm_lds8(tbB, Wfw + 1 * 65536, swz, hi, lo, acc);
#pragma unroll
    for (int m = 0; m < 4; m++)
#pragma unroll
        for (int n = 0; n < 2; n++)
#pragma unroll
            for (int j = 0; j < 4; j++) {
                int r = m * 16 + hi * 4 + j;
                int cc = w * 32 + n * 16 + lo;
                char* p = xbB + r * 512 + ((cc * 2) ^ ((r & 7) << 4));
                float xn = (bf2f(*(u16*)p) + ssilu(acc[m][n][j])) * INV_SQRT2;
                *(u16*)p = f2bf(xn);
            }
    __syncthreads();

    // G3: t1 = ssilu(x @ W2a) -> tb
    gemm_lds8(xbB, Wfw + 2 * 65536, swz, hi, lo, acc);
#pragma unroll
    for (int m = 0; m < 4; m++)
#pragma unroll
        for (int n = 0; n < 2; n++)
#pragma unroll
            for (int j = 0; j < 4; j++) {
                int r = m * 16 + hi * 4 + j;
                int cc = w * 32 + n * 16 + lo;
                *(u16*)(tbB + r * 512 + ((cc * 2) ^ ((r & 7) << 4))) =
                    f2bf(ssilu(acc[m][n][j]));
            }
    __syncthreads();

    // G4: x_final = (x + ssilu(t1 @ W2b)) * INV_SQRT2, fp32 in regs
    gemm_lds8(tbB, Wfw + 3 * 65536, swz, hi, lo, acc);
    float wo[2];
#pragma unroll
    for (int n = 0; n < 2; n++) wo[n] = Wout[w * 32 + n * 16 + lo];

    float part[4][4];
#pragma unroll
    for (int m = 0; m < 4; m++)
#pragma unroll
        for (int j = 0; j < 4; j++) part[m][j] = 0.f;
#pragma unroll
    for (int m = 0; m < 4; m++)
#pragma unroll
        for (int n = 0; n < 2; n++)
#pragma unroll
            for (int j = 0; j < 4; j++) {
                int r = m * 16 + hi * 4 + j;
                int cc = w * 32 + n * 16 + lo;
                const char* p = xbB + r * 512 + ((cc * 2) ^ ((r & 7) << 4));
                float xf = (bf2f(*(const u16*)p) + ssilu(acc[m][n][j])) * INV_SQRT2;
                part[m][j] += xf * wo[n];
            }
#pragma unroll
    for (int m = 0; m < 4; m++)
#pragma unroll
        for (int j = 0; j < 4; j++) {
            float v = part[m][j];
            v += __shfl_xor(v, 1);
            v += __shfl_xor(v, 2);
            v += __shfl_xor(v, 4);
            v += __shfl_xor(v, 8);
            if (lo == 0) fpart[w][m * 16 + hi * 4 + j] = v;
        }
    __syncthreads();

    if (t < 64) {
        int r = t;
        float F = fpart[0][r] + fpart[1][r] + fpart[2][r] + fpart[3][r] +
                  fpart[4][r] + fpart[5][r] + fpart[6][r] + fpart[7][r];
        long e = rowbase + r;
        float vx = evec[e * 3 + 0], vy = evec[e * 3 + 1], vz = evec[e * 3 + 2];
        int a = eidx[e];
        atomicAdd(&out[a * 3 + 0], F * vx);
        atomicAdd(&out[a * 3 + 1], F * vy);
        atomicAdd(&out[a * 3 + 2], F * vz);
    }
}

extern "C" void kernel_launch(void* const* d_in, const int* in_sizes, int n_in,
                              void* d_out, int out_size, void* d_ws, size_t ws_size,
                              hipStream_t stream) {
    const float* x_cat = (const float*)d_in[0];
    const float* evec  = (const float*)d_in[1];
    const int*   eidx  = (const int*)d_in[2];
    const float* Win   = (const float*)d_in[3];
    const float* W1a   = (const float*)d_in[4];
    const float* W1b   = (const float*)d_in[5];
    const float* W2a   = (const float*)d_in[6];
    const float* W2b   = (const float*)d_in[7];
    const float* Wout  = (const float*)d_in[8];
    float* out = (float*)d_out;
    const int E = in_sizes[1] / 3;   // 200000

    u16* WinF  = (u16*)d_ws;          // 327680 elems
    u16* Wfrag = WinF + 327680;       // 262144 elems

    int prepN = 327680 + 262144 + out_size;
    prep_kernel<<<(prepN + 255) / 256, 256, 0, stream>>>(
        Win, W1a, W1b, W2a, W2b, WinF, Wfrag, out, out_size);
    fused_kernel<<<E / 64, 512, 0, stream>>>(
        x_cat, WinF, Wfrag, Wout, evec, eidx, out);
}